// Round 1
// baseline (812.618 us; speedup 1.0000x reference)
//
#include <hip/hip_runtime.h>
#include <stdint.h>

// Problem constants
#define TT     48000   // T
#define TK     120     // samples per chunk (T/K)
#define NC     128     // CIN == COUT
#define NA     384     // CIN*KS
#define NZ     64
#define NH     32
#define NK     400
#define NCHUNK 1600    // B*K
#define MW     49152   // CIN*COUT*KS
#define XROWS  48002   // T + 2 zero prefix rows (causal taps)

typedef float f32x4 __attribute__((ext_vector_type(4)));
typedef __bf16 bf16x8 __attribute__((ext_vector_type(8)));

static __device__ __forceinline__ uint16_t f2bf(float f) {
    uint32_t x; __builtin_memcpy(&x, &f, 4);
    return (uint16_t)((x + 0x7fffu + ((x >> 16) & 1u)) >> 16);
}
static __device__ __forceinline__ uint32_t pk2(uint16_t lo, uint16_t hi) {
    return (uint32_t)lo | ((uint32_t)hi << 16);
}

// ---------------------------------------------------------------------------
// k0w: permute+convert w2 -> w2p bf16 [m'][32], m' = c*384 + a  (m = a*128+c)
//      and b2 -> b2p f32 [m'].
// ---------------------------------------------------------------------------
__global__ __launch_bounds__(256) void k0w(
    const float* __restrict__ w2, const float* __restrict__ b2,
    uint16_t* __restrict__ w2p, float* __restrict__ b2p) {
    int m = blockIdx.x * 256 + threadIdx.x;   // 0..49151
    int a = m >> 7, c = m & 127;
    int mp = c * NA + a;
    const float* src = w2 + (size_t)m * NH;
    uint16_t* dst = w2p + (size_t)mp * NH;
#pragma unroll
    for (int i = 0; i < NH; i += 8) {
        float4 v0 = *(const float4*)(src + i);
        float4 v1 = *(const float4*)(src + i + 4);
        uint4 o;
        o.x = pk2(f2bf(v0.x), f2bf(v0.y));
        o.y = pk2(f2bf(v0.z), f2bf(v0.w));
        o.z = pk2(f2bf(v1.x), f2bf(v1.y));
        o.w = pk2(f2bf(v1.z), f2bf(v1.w));
        *(uint4*)(dst + i) = o;
    }
    b2p[mp] = b2[m];
}

// ---------------------------------------------------------------------------
// k0x: transpose x[b][cin][t] f32 -> Xt[b][t+2][cin] bf16 (2 zero prefix rows)
// tile: 128 t x 64 cin per block
// ---------------------------------------------------------------------------
__global__ __launch_bounds__(256) void k0x(
    const float* __restrict__ x, uint16_t* __restrict__ Xt) {
    int t0 = blockIdx.x * 128, cin0 = blockIdx.y * 64, b = blockIdx.z;
    int tid = threadIdx.x;
    __shared__ __align__(16) uint16_t Lt[128][72];   // pad row to 72 (144B)
    const float* xb = x + ((size_t)b * NC + cin0) * TT + t0;
    int cg = (tid & 7) * 8;    // local cin base (0..56)
    int tq = (tid >> 3) * 4;   // local t base   (0..124)
    uint16_t vb[4][8];         // [t][cin]
#pragma unroll
    for (int i = 0; i < 8; ++i) {
        float4 v = *(const float4*)(xb + (size_t)(cg + i) * TT + tq);
        vb[0][i] = f2bf(v.x); vb[1][i] = f2bf(v.y);
        vb[2][i] = f2bf(v.z); vb[3][i] = f2bf(v.w);
    }
#pragma unroll
    for (int j = 0; j < 4; ++j) {
        uint4 o; __builtin_memcpy(&o, vb[j], 16);
        *(uint4*)&Lt[tq + j][cg] = o;
    }
    __syncthreads();
    uint16_t* XtB = Xt + (size_t)b * XROWS * NC;
#pragma unroll
    for (int r = 0; r < 4; ++r) {
        int s = r * 256 + tid;
        int t = s >> 3, cc = s & 7;
        uint4 o = *(uint4*)&Lt[t][cc * 8];
        *(uint4*)(XtB + (size_t)(t0 + t + 2) * NC + cin0 + cc * 8) = o;
    }
    if (blockIdx.x == 0 && blockIdx.y == 0 && tid < 32)
        *(uint4*)(XtB + tid * 8) = make_uint4(0, 0, 0, 0);  // zero rows -2,-1
}

// ---------------------------------------------------------------------------
// k1: 4 chunks per block (one per wave). All weights staged in LDS with
// conflict-free layouts; coalesced global loads.
// ---------------------------------------------------------------------------
__global__ __launch_bounds__(256) void k1_hidden(
    const float* __restrict__ z,
    const float* __restrict__ w1, const float* __restrict__ b1,
    const float* __restrict__ bw1, const float* __restrict__ bb1,
    const float* __restrict__ bw2, const float* __restrict__ bb2,
    uint16_t* __restrict__ Hb, float* __restrict__ biasws) {
    int tid = threadIdx.x, lane = tid & 63, w = tid >> 6;
    int chunk0 = blockIdx.x * 4;
    int b = chunk0 / NK;            // 400 % 4 == 0: all 4 chunks same b
    int k0 = chunk0 - b * NK;

    __shared__ float w1sT[64][33];   // [i][h] transposed, conflict-free reads
    __shared__ float bw1sT[64][33];
    __shared__ float bw2s[128][33];  // [c][j]
    __shared__ float zs[64][4];
    __shared__ float hbs[4][33];
    __shared__ float b1s[32], bb1s[32], bb2s[128];

    {   // stage w1, bw1 (transposed)
        int row = tid >> 3, c0 = (tid & 7) * 8;
        float4 a0 = *(const float4*)(w1 + row * NZ + c0);
        float4 a1 = *(const float4*)(w1 + row * NZ + c0 + 4);
        float4 c0v = *(const float4*)(bw1 + row * NZ + c0);
        float4 c1v = *(const float4*)(bw1 + row * NZ + c0 + 4);
        const float av[8] = {a0.x,a0.y,a0.z,a0.w,a1.x,a1.y,a1.z,a1.w};
        const float cv[8] = {c0v.x,c0v.y,c0v.z,c0v.w,c1v.x,c1v.y,c1v.z,c1v.w};
#pragma unroll
        for (int j = 0; j < 8; ++j) {
            w1sT[c0 + j][row]  = av[j];
            bw1sT[c0 + j][row] = cv[j];
        }
    }
    {   // stage bw2 [128][32]
        int r = tid >> 1, cb = (tid & 1) * 16;
        float4 v0 = *(const float4*)(bw2 + r * NH + cb);
        float4 v1 = *(const float4*)(bw2 + r * NH + cb + 4);
        float4 v2 = *(const float4*)(bw2 + r * NH + cb + 8);
        float4 v3 = *(const float4*)(bw2 + r * NH + cb + 12);
        const float vv[16] = {v0.x,v0.y,v0.z,v0.w,v1.x,v1.y,v1.z,v1.w,
                              v2.x,v2.y,v2.z,v2.w,v3.x,v3.y,v3.z,v3.w};
#pragma unroll
        for (int j = 0; j < 16; ++j) bw2s[r][cb + j] = vv[j];
    }
    if (tid < 64) {
        float4 zv = *(const float4*)(z + ((size_t)b * NZ + tid) * NK + k0);
        zs[tid][0] = zv.x; zs[tid][1] = zv.y; zs[tid][2] = zv.z; zs[tid][3] = zv.w;
    }
    if (tid < 32) { b1s[tid] = b1[tid]; bb1s[tid] = bb1[tid]; }
    if (tid >= 128 && tid < 256) bb2s[tid - 128] = bb2[tid - 128];
    __syncthreads();

    int chunk = chunk0 + w;
    if (lane < NH) {
        float s = b1s[lane];
#pragma unroll
        for (int i = 0; i < NZ; ++i) s = fmaf(w1sT[i][lane], zs[i][w], s);
        Hb[(size_t)chunk * NH + lane] = f2bf(fmaxf(s, 0.f));
    } else {
        int j = lane - NH;
        float s = bb1s[j];
#pragma unroll
        for (int i = 0; i < NZ; ++i) s = fmaf(bw1sT[i][j], zs[i][w], s);
        hbs[w][j] = fmaxf(s, 0.f);
    }

#pragma unroll
    for (int r = 0; r < 2; ++r) {
        int c = r * 64 + lane;
        float s = bb2s[c];
#pragma unroll
        for (int j = 0; j < NH; ++j) s = fmaf(bw2s[c][j], hbs[w][j], s);
        biasws[(size_t)chunk * NC + c] = s;
    }
}

// ---------------------------------------------------------------------------
// k23_fused: fused weight-gen + conv GEMM. Block = 8 consecutive chunks x
// 16 couts (grid 200 x 8). Two a-half passes (192 a each):
//   wgen: MFMA w2p-slice x Hb -> bf16 weights into LDS (48 KB),
//         LDS c-index XOR'ed with ch for conflict-free write AND read.
//   main: per chunk, A-fragments read directly from L2/L3-resident Xt,
//         B-fragments from LDS; acc[8 ch][2 tt] persists across passes.
// No Wt materialization, no per-dk staging barriers (3 barriers/block).
// ---------------------------------------------------------------------------
__global__ __launch_bounds__(256, 2) void k23_fused(
    const uint16_t* __restrict__ w2p, const float* __restrict__ b2p,
    const uint16_t* __restrict__ Hb, const uint16_t* __restrict__ Xt,
    const float* __restrict__ biasws, float* __restrict__ out) {
    int tid = threadIdx.x, lane = tid & 63, w = tid >> 6;
    int quad = lane >> 4, li = lane & 15;
    int gx = blockIdx.x;          // chunk group (8 chunks): 0..199
    int gy = blockIdx.y;          // cout group (16 couts): 0..7
    int chunk0 = gx * 8;
    int b = chunk0 / NK;          // 8 | 400: all chunks same b
    int kb0 = (chunk0 - b * NK) * TK;
    int c0 = gy * 16;
    size_t m0 = (size_t)c0 * NA;  // w2p row base for this cout group

    // Wlds[ch][agrp 0..23][c^ch][8 a] bf16 = 48 KB
    __shared__ __align__(16) uint16_t Wlds[8][24][16][8];

    // wgen B fragment: 8 chunks (cols 8..15 duplicate 0..7, masked on store)
    bf16x8 hfrag = *(const bf16x8*)(Hb + (size_t)(chunk0 + (li & 7)) * NH + quad * 8);
    const uint16_t* XtB = Xt + (size_t)b * XROWS * NC;

    f32x4 acc[8][2];
#pragma unroll
    for (int i = 0; i < 8; ++i) {
        acc[i][0] = (f32x4){0.f, 0.f, 0.f, 0.f};
        acc[i][1] = (f32x4){0.f, 0.f, 0.f, 0.f};
    }
    int tb = w * 32;   // wave's t base within chunk

#pragma unroll
    for (int p = 0; p < 2; ++p) {
        if (p) __syncthreads();   // main pass 0 reads done before overwrite
        // ---- wgen: a in [p*192, p*192+192) for 16 couts x 8 chunks
#pragma unroll
        for (int j = 0; j < 48; ++j) {
            int mt = j * 4 + w;            // tile 0..191
            int cl = mt / 12;              // local cout 0..15
            int al = (mt % 12) * 16;       // a base within half, 0..176
            bf16x8 afrag = *(const bf16x8*)(
                w2p + (m0 + (size_t)cl * NA + p * 192 + al + li) * NH + quad * 8);
            f32x4 z4 = {0.f, 0.f, 0.f, 0.f};
            f32x4 d = __builtin_amdgcn_mfma_f32_16x16x32_bf16(afrag, hfrag, z4, 0, 0, 0);
            float4 bias = *(const float4*)(b2p + m0 + cl * NA + p * 192 + al + quad * 4);
            if (li < 8) {                  // D col = chunk = li (0..7 valid)
                uint16_t pk[4] = { f2bf(d[0] + bias.x), f2bf(d[1] + bias.y),
                                   f2bf(d[2] + bias.z), f2bf(d[3] + bias.w) };
                uint64_t pv; __builtin_memcpy(&pv, pk, 8);
                *(uint64_t*)&Wlds[li][(al >> 3) + (quad >> 1)][cl ^ li][(quad & 1) * 4] = pv;
            }
        }
        __syncthreads();
        // ---- main GEMM: 8 chunks x 6 k-steps (192 a this pass)
#pragma unroll
        for (int ch = 0; ch < 8; ++ch) {
            const uint16_t* row0 = XtB + (size_t)(kb0 + ch * TK + tb + li + 2) * NC;
#pragma unroll
            for (int s = 0; s < 6; ++s) {
                int ag = p * 192 + s * 32 + quad * 8;      // global a of this slice
                int off = (ag & 127) - (ag >> 7) * NC;     // cin - tap*row
                bf16x8 bfr = *(const bf16x8*)&Wlds[ch][s * 4 + quad][li ^ ch][0];
                bf16x8 a0 = *(const bf16x8*)(row0 + off);
                bf16x8 a1 = *(const bf16x8*)(row0 + 16 * NC + off);
                acc[ch][0] = __builtin_amdgcn_mfma_f32_16x16x32_bf16(a0, bfr, acc[ch][0], 0, 0, 0);
                acc[ch][1] = __builtin_amdgcn_mfma_f32_16x16x32_bf16(a1, bfr, acc[ch][1], 0, 0, 0);
            }
        }
    }

    // ---- epilogue: D col = cout = li, row = t = tb + tt*16 + quad*4 + r
    int cg = c0 + li;
    int t0 = tb + quad * 4;
#pragma unroll
    for (int ch = 0; ch < 8; ++ch) {
        int chunk = chunk0 + ch;
        float bias = biasws[(size_t)chunk * NC + cg];
        float* ob = out + ((size_t)b * NC + cg) * TT + kb0 + ch * TK;
        f32x4 v0 = acc[ch][0];
        *(float4*)(ob + t0) = make_float4(v0[0] + bias, v0[1] + bias,
                                          v0[2] + bias, v0[3] + bias);
        if (t0 + 16 < TK) {    // only wave 3 tt=1 quads 2,3 exceed 120
            f32x4 v1 = acc[ch][1];
            *(float4*)(ob + t0 + 16) = make_float4(v1[0] + bias, v1[1] + bias,
                                                   v1[2] + bias, v1[3] + bias);
        }
    }
}

// ---------------------------------------------------------------------------
// launch
// ---------------------------------------------------------------------------
extern "C" void kernel_launch(void* const* d_in, const int* in_sizes, int n_in,
                              void* d_out, int out_size, void* d_ws, size_t ws_size,
                              hipStream_t stream) {
    const float* x   = (const float*)d_in[0];
    const float* z   = (const float*)d_in[1];
    const float* w1  = (const float*)d_in[2];
    const float* b1  = (const float*)d_in[3];
    const float* w2  = (const float*)d_in[4];
    const float* b2  = (const float*)d_in[5];
    const float* bw1 = (const float*)d_in[6];
    const float* bb1 = (const float*)d_in[7];
    const float* bw2 = (const float*)d_in[8];
    const float* bb2 = (const float*)d_in[9];
    float* out = (float*)d_out;

    // ws layout (all 256-aligned):
    char* ws = (char*)d_ws;
    uint16_t* Hb     = (uint16_t*)(ws);                 //   102,400 B
    float*    biasws = (float*)(ws + 102400);           //   819,200 B
    uint16_t* w2p    = (uint16_t*)(ws + 921600);        // 3,145,728 B
    float*    b2p    = (float*)(ws + 4067328);          //   196,608 B
    uint16_t* Xt     = (uint16_t*)(ws + 4263936);       // 49,158,144 B (incl. tail pad)

    k0w<<<MW / 256, 256, 0, stream>>>(w2, b2, w2p, b2p);
    k0x<<<dim3(TT / 128, 2, 4), 256, 0, stream>>>(x, Xt);
    k1_hidden<<<NCHUNK / 4, 256, 0, stream>>>(z, w1, b1, bw1, bb1, bw2, bb2, Hb, biasws);
    k23_fused<<<dim3(200, 8), 256, 0, stream>>>(w2p, b2p, Hb, Xt, biasws, out);
}

// Round 2
// 310.013 us; speedup vs baseline: 2.6212x; 2.6212x over previous
//
#include <hip/hip_runtime.h>
#include <stdint.h>

// Problem constants
#define TT     48000   // T
#define TK     120     // samples per chunk (T/K)
#define NC     128     // CIN == COUT
#define NA     384     // CIN*KS
#define NZ     64
#define NH     32
#define NK     400
#define NCHUNK 1600    // B*K
#define MW     49152   // CIN*COUT*KS
#define XROWS  48002   // T + 2 zero prefix rows (causal taps)

typedef float f32x4 __attribute__((ext_vector_type(4)));
typedef __bf16 bf16x8 __attribute__((ext_vector_type(8)));

static __device__ __forceinline__ uint16_t f2bf(float f) {
    uint32_t x; __builtin_memcpy(&x, &f, 4);
    return (uint16_t)((x + 0x7fffu + ((x >> 16) & 1u)) >> 16);
}
static __device__ __forceinline__ uint32_t pk2(uint16_t lo, uint16_t hi) {
    return (uint32_t)lo | ((uint32_t)hi << 16);
}

// ---------------------------------------------------------------------------
// k0w: permute+convert w2 -> w2p bf16 [m'][32], m' = c*384 + a  (m = a*128+c)
//      and b2 -> b2p f32 [m'].
// ---------------------------------------------------------------------------
__global__ __launch_bounds__(256) void k0w(
    const float* __restrict__ w2, const float* __restrict__ b2,
    uint16_t* __restrict__ w2p, float* __restrict__ b2p) {
    int m = blockIdx.x * 256 + threadIdx.x;   // 0..49151
    int a = m >> 7, c = m & 127;
    int mp = c * NA + a;
    const float* src = w2 + (size_t)m * NH;
    uint16_t* dst = w2p + (size_t)mp * NH;
#pragma unroll
    for (int i = 0; i < NH; i += 8) {
        float4 v0 = *(const float4*)(src + i);
        float4 v1 = *(const float4*)(src + i + 4);
        uint4 o;
        o.x = pk2(f2bf(v0.x), f2bf(v0.y));
        o.y = pk2(f2bf(v0.z), f2bf(v0.w));
        o.z = pk2(f2bf(v1.x), f2bf(v1.y));
        o.w = pk2(f2bf(v1.z), f2bf(v1.w));
        *(uint4*)(dst + i) = o;
    }
    b2p[mp] = b2[m];
}

// ---------------------------------------------------------------------------
// k0x: transpose x[b][cin][t] f32 -> Xt[b][t+2][cin] bf16 (2 zero prefix rows)
// tile: 128 t x 64 cin per block
// ---------------------------------------------------------------------------
__global__ __launch_bounds__(256) void k0x(
    const float* __restrict__ x, uint16_t* __restrict__ Xt) {
    int t0 = blockIdx.x * 128, cin0 = blockIdx.y * 64, b = blockIdx.z;
    int tid = threadIdx.x;
    __shared__ __align__(16) uint16_t Lt[128][72];   // pad row to 72 (144B)
    const float* xb = x + ((size_t)b * NC + cin0) * TT + t0;
    int cg = (tid & 7) * 8;    // local cin base (0..56)
    int tq = (tid >> 3) * 4;   // local t base   (0..124)
    uint16_t vb[4][8];         // [t][cin]
#pragma unroll
    for (int i = 0; i < 8; ++i) {
        float4 v = *(const float4*)(xb + (size_t)(cg + i) * TT + tq);
        vb[0][i] = f2bf(v.x); vb[1][i] = f2bf(v.y);
        vb[2][i] = f2bf(v.z); vb[3][i] = f2bf(v.w);
    }
#pragma unroll
    for (int j = 0; j < 4; ++j) {
        uint4 o; __builtin_memcpy(&o, vb[j], 16);
        *(uint4*)&Lt[tq + j][cg] = o;
    }
    __syncthreads();
    uint16_t* XtB = Xt + (size_t)b * XROWS * NC;
#pragma unroll
    for (int r = 0; r < 4; ++r) {
        int s = r * 256 + tid;
        int t = s >> 3, cc = s & 7;
        uint4 o = *(uint4*)&Lt[t][cc * 8];
        *(uint4*)(XtB + (size_t)(t0 + t + 2) * NC + cin0 + cc * 8) = o;
    }
    if (blockIdx.x == 0 && blockIdx.y == 0 && tid < 32)
        *(uint4*)(XtB + tid * 8) = make_uint4(0, 0, 0, 0);  // zero rows -2,-1
}

// ---------------------------------------------------------------------------
// k1: 4 chunks per block (one per wave). All weights staged in LDS with
// conflict-free layouts; coalesced global loads.
// ---------------------------------------------------------------------------
__global__ __launch_bounds__(256) void k1_hidden(
    const float* __restrict__ z,
    const float* __restrict__ w1, const float* __restrict__ b1,
    const float* __restrict__ bw1, const float* __restrict__ bb1,
    const float* __restrict__ bw2, const float* __restrict__ bb2,
    uint16_t* __restrict__ Hb, float* __restrict__ biasws) {
    int tid = threadIdx.x, lane = tid & 63, w = tid >> 6;
    int chunk0 = blockIdx.x * 4;
    int b = chunk0 / NK;            // 400 % 4 == 0: all 4 chunks same b
    int k0 = chunk0 - b * NK;

    __shared__ float w1sT[64][33];   // [i][h] transposed, conflict-free reads
    __shared__ float bw1sT[64][33];
    __shared__ float bw2s[128][33];  // [c][j]
    __shared__ float zs[64][4];
    __shared__ float hbs[4][33];
    __shared__ float b1s[32], bb1s[32], bb2s[128];

    {   // stage w1, bw1 (transposed)
        int row = tid >> 3, c0 = (tid & 7) * 8;
        float4 a0 = *(const float4*)(w1 + row * NZ + c0);
        float4 a1 = *(const float4*)(w1 + row * NZ + c0 + 4);
        float4 c0v = *(const float4*)(bw1 + row * NZ + c0);
        float4 c1v = *(const float4*)(bw1 + row * NZ + c0 + 4);
        const float av[8] = {a0.x,a0.y,a0.z,a0.w,a1.x,a1.y,a1.z,a1.w};
        const float cv[8] = {c0v.x,c0v.y,c0v.z,c0v.w,c1v.x,c1v.y,c1v.z,c1v.w};
#pragma unroll
        for (int j = 0; j < 8; ++j) {
            w1sT[c0 + j][row]  = av[j];
            bw1sT[c0 + j][row] = cv[j];
        }
    }
    {   // stage bw2 [128][32]
        int r = tid >> 1, cb = (tid & 1) * 16;
        float4 v0 = *(const float4*)(bw2 + r * NH + cb);
        float4 v1 = *(const float4*)(bw2 + r * NH + cb + 4);
        float4 v2 = *(const float4*)(bw2 + r * NH + cb + 8);
        float4 v3 = *(const float4*)(bw2 + r * NH + cb + 12);
        const float vv[16] = {v0.x,v0.y,v0.z,v0.w,v1.x,v1.y,v1.z,v1.w,
                              v2.x,v2.y,v2.z,v2.w,v3.x,v3.y,v3.z,v3.w};
#pragma unroll
        for (int j = 0; j < 16; ++j) bw2s[r][cb + j] = vv[j];
    }
    if (tid < 64) {
        float4 zv = *(const float4*)(z + ((size_t)b * NZ + tid) * NK + k0);
        zs[tid][0] = zv.x; zs[tid][1] = zv.y; zs[tid][2] = zv.z; zs[tid][3] = zv.w;
    }
    if (tid < 32) { b1s[tid] = b1[tid]; bb1s[tid] = bb1[tid]; }
    if (tid >= 128 && tid < 256) bb2s[tid - 128] = bb2[tid - 128];
    __syncthreads();

    int chunk = chunk0 + w;
    if (lane < NH) {
        float s = b1s[lane];
#pragma unroll
        for (int i = 0; i < NZ; ++i) s = fmaf(w1sT[i][lane], zs[i][w], s);
        Hb[(size_t)chunk * NH + lane] = f2bf(fmaxf(s, 0.f));
    } else {
        int j = lane - NH;
        float s = bb1s[j];
#pragma unroll
        for (int i = 0; i < NZ; ++i) s = fmaf(bw1sT[i][j], zs[i][w], s);
        hbs[w][j] = fmaxf(s, 0.f);
    }

#pragma unroll
    for (int r = 0; r < 2; ++r) {
        int c = r * 64 + lane;
        float s = bb2s[c];
#pragma unroll
        for (int j = 0; j < NH; ++j) s = fmaf(bw2s[c][j], hbs[w][j], s);
        biasws[(size_t)chunk * NC + c] = s;
    }
}

// ---------------------------------------------------------------------------
// k2: MFMA weight materialization with LDS-staged coalesced stores.
// Wave computes 16 tiles (256 m' x 16 chunks), stashes bf16 results in
// LDS [16 chunk][264], then writes 256B-contiguous runs per chunk row.
// ---------------------------------------------------------------------------
__global__ __launch_bounds__(256) void k2_wgen(
    const uint16_t* __restrict__ w2p, const float* __restrict__ b2p,
    const uint16_t* __restrict__ Hb, uint16_t* __restrict__ Wt,
    int chunk0, int nchunk) {
    int tid = threadIdx.x, lane = tid & 63, w = tid >> 6;
    int quad = lane >> 4, li = lane & 15;
    __shared__ __align__(16) uint16_t St[4][16][264];  // pad 256->264: 2-way max

    int clocal = blockIdx.y * 16 + li;
    int cl = clocal < nchunk ? clocal : (nchunk - 1);
    bf16x8 bfrag = *(const bf16x8*)(Hb + (size_t)(chunk0 + cl) * NH + quad * 8);
    int mbase = blockIdx.x * 1024 + w * 256;

#pragma unroll
    for (int t = 0; t < 16; ++t) {
        int mb = mbase + t * 16;
        bf16x8 afrag = *(const bf16x8*)(w2p + (size_t)(mb + li) * NH + quad * 8);
        f32x4 acc = {0.f, 0.f, 0.f, 0.f};
        acc = __builtin_amdgcn_mfma_f32_16x16x32_bf16(afrag, bfrag, acc, 0, 0, 0);
        float4 bias = *(const float4*)(b2p + mb + quad * 4);
        uint16_t p[4] = { f2bf(acc[0] + bias.x), f2bf(acc[1] + bias.y),
                          f2bf(acc[2] + bias.z), f2bf(acc[3] + bias.w) };
        uint64_t pv; __builtin_memcpy(&pv, p, 8);
        *(uint64_t*)&St[w][li][t * 16 + quad * 4] = pv;   // D: row=quad*4+r, col(chunk)=li
    }
    // same-wave LDS readback (compiler inserts lgkmcnt wait; no barrier needed)
#pragma unroll
    for (int p = 0; p < 8; ++p) {
        int ch = (lane >> 4) + (p & 3) * 4;
        int part = lane & 15, mh = p >> 2;
        uint4 v = *(const uint4*)&St[w][ch][mh * 128 + part * 8];
        int cg = blockIdx.y * 16 + ch;
        if (cg < nchunk)
            *(uint4*)(Wt + (size_t)cg * MW + mbase + mh * 128 + part * 8) = v;
    }
}

// ---------------------------------------------------------------------------
// k3: per-chunk conv GEMM via MFMA. Block = chunk, 4 waves, each 64t x 64c.
// NEW vs round-0: raw Xt rows staged ONCE in LDS (32 KB, XOR-swizzled via
// pre-swizzled global source per rule #21) — removes the 3x tap-duplicated
// per-dk A staging (loop staging 192->128 KB/block). Taps resolved at
// ds_read time: row = t+2-tap, chunk read at (q ^ (row&15)) -> 2-way max
// bank aliasing (free). Rows >127 clamp to 127 (feed only discarded t>=126).
// W staged per dk (16 KB) as before. LDS 48 KB -> 3 blocks/CU.
// ---------------------------------------------------------------------------
__global__ __launch_bounds__(256) void k3_conv(
    const uint16_t* __restrict__ Xt, const uint16_t* __restrict__ Wt,
    const float* __restrict__ biasws, float* __restrict__ out, int chunk0) {
    int cl = blockIdx.x, chunk = chunk0 + cl;
    int b = chunk / NK, k = chunk - b * NK;
    int kbase = k * TK;
    int tid = threadIdx.x, lane = tid & 63, w = tid >> 6;
    int quad = lane >> 4, li = lane & 15;
    int tblk = (w & 1) * 64, cblk = (w >> 1) * 64;

    __shared__ __align__(16) char smem[49152];
    char* Xa = smem;            // 128 rows x 16 chunks x 16B, chunk^=(row&15)
    char* Ws = smem + 32768;    // 8 kc x 128 c x 16B
    const uint16_t* XtB = Xt + (size_t)b * XROWS * NC;
    const uint16_t* WtC = Wt + (size_t)cl * MW;

    f32x4 acc[4][4];
#pragma unroll
    for (int i = 0; i < 4; ++i)
#pragma unroll
        for (int j = 0; j < 4; ++j) acc[i][j] = (f32x4){0.f, 0.f, 0.f, 0.f};

    // prologue: stage raw rows kbase..kbase+127 (global row = kbase + r maps
    // to Xa[r]; reads use r = t + 2 - tap). Source chunk pre-swizzled so the
    // linear global_load_lds dest yields the swizzled LDS layout.
#pragma unroll
    for (int i = 0; i < 8; ++i) {
        int brow = w * 32 + i * 4 + quad;
        const uint16_t* g = XtB + (size_t)(kbase + brow) * NC
                          + ((li ^ (brow & 15)) * 8);
        __builtin_amdgcn_global_load_lds(
            (__attribute__((address_space(1))) void*)g,
            (__attribute__((address_space(3))) void*)(Xa + (w * 32 + i * 4) * 256),
            16, 0, 0);
    }

    {   // stage W for dk=0
        int a0 = 0;
#pragma unroll
        for (int i = 0; i < 4; ++i) {
            int kc = 2 * w + (i >> 1), half = i & 1;
            int c = half * 64 + lane;
            const uint16_t* g = WtC + (size_t)c * NA + a0 + kc * 8;
            __builtin_amdgcn_global_load_lds(
                (__attribute__((address_space(1))) void*)g,
                (__attribute__((address_space(3))) void*)(Ws + kc * 2048 + half * 1024),
                16, 0, 0);
        }
    }
    __syncthreads();   // drains Xa + Ws(0)

#pragma unroll
    for (int dk = 0; dk < 6; ++dk) {
        int tap = dk >> 1;
#pragma unroll
        for (int s = 0; s < 2; ++s) {
            bf16x8 af[4], bfr[4];
#pragma unroll
            for (int tt = 0; tt < 4; ++tt) {
                int r = tblk + tt * 16 + li + 2 - tap;
                r = r > 127 ? 127 : r;     // clamped rows feed only t>=126 (discarded)
                int q = (dk & 1) * 8 + s * 4 + quad;
                af[tt] = *(const bf16x8*)(Xa + r * 256 + ((q ^ (r & 15)) << 4));
            }
#pragma unroll
            for (int ct = 0; ct < 4; ++ct)
                bfr[ct] = *(const bf16x8*)(Ws + (s * 4 + quad) * 2048 + (cblk + ct * 16 + li) * 16);
#pragma unroll
            for (int tt = 0; tt < 4; ++tt)
#pragma unroll
                for (int ct = 0; ct < 4; ++ct)
                    acc[tt][ct] = __builtin_amdgcn_mfma_f32_16x16x32_bf16(
                        af[tt], bfr[ct], acc[tt][ct], 0, 0, 0);
        }
        __syncthreads();                  // all reads of Ws(dk) done
        if (dk < 5) {
            int a0 = (dk + 1) * 64;
#pragma unroll
            for (int i = 0; i < 4; ++i) {
                int kc = 2 * w + (i >> 1), half = i & 1;
                int c = half * 64 + lane;
                const uint16_t* g = WtC + (size_t)c * NA + a0 + kc * 8;
                __builtin_amdgcn_global_load_lds(
                    (__attribute__((address_space(1))) void*)g,
                    (__attribute__((address_space(3))) void*)(Ws + kc * 2048 + half * 1024),
                    16, 0, 0);
            }
            __syncthreads();              // drains Ws(dk+1)
        }
    }

    // epilogue: D col = c = lane&15 (+tile), row = t = quad*4+reg (+tile)
#pragma unroll
    for (int ct = 0; ct < 4; ++ct) {
        int c = cblk + ct * 16 + li;
        float bias = biasws[(size_t)chunk * NC + c];
        float* ob = out + ((size_t)b * NC + c) * TT + kbase;
#pragma unroll
        for (int tt = 0; tt < 4; ++tt) {
            int t0v = tblk + tt * 16 + quad * 4;
            if (t0v < TK) {
                f32x4 v = acc[tt][ct];
                *(float4*)(ob + t0v) = make_float4(v[0] + bias, v[1] + bias,
                                                   v[2] + bias, v[3] + bias);
            }
        }
    }
}

// ---------------------------------------------------------------------------
// launch
// ---------------------------------------------------------------------------
extern "C" void kernel_launch(void* const* d_in, const int* in_sizes, int n_in,
                              void* d_out, int out_size, void* d_ws, size_t ws_size,
                              hipStream_t stream) {
    const float* x   = (const float*)d_in[0];
    const float* z   = (const float*)d_in[1];
    const float* w1  = (const float*)d_in[2];
    const float* b1  = (const float*)d_in[3];
    const float* w2  = (const float*)d_in[4];
    const float* b2  = (const float*)d_in[5];
    const float* bw1 = (const float*)d_in[6];
    const float* bb1 = (const float*)d_in[7];
    const float* bw2 = (const float*)d_in[8];
    const float* bb2 = (const float*)d_in[9];
    float* out = (float*)d_out;

    // ws layout (all 256-aligned):
    char* ws = (char*)d_ws;
    uint16_t* Hb     = (uint16_t*)(ws);                 //   102,400 B
    float*    biasws = (float*)(ws + 102400);           //   819,200 B
    uint16_t* w2p    = (uint16_t*)(ws + 921600);        // 3,145,728 B
    float*    b2p    = (float*)(ws + 4067328);          //   196,608 B
    uint16_t* Xt     = (uint16_t*)(ws + 4263936);       // 49,158,144 B (incl. tail pad)
    const size_t wt_off = 53422080;
    uint16_t* Wt     = (uint16_t*)(ws + wt_off);        // slice buffer

    // L3 blocking: keep the Wt slice resident in Infinity Cache between
    // k2 (producer) and k3 (consumer). 800 chunks -> 78.6 MB slice.
    size_t avail = (ws_size > wt_off) ? (ws_size - wt_off) : 0;
    int batch = (int)(avail / ((size_t)MW * 2));
    if (batch > 800) batch = 800;
    if (batch < 1) batch = 1;

    k0w<<<MW / 256, 256, 0, stream>>>(w2, b2, w2p, b2p);
    k0x<<<dim3(TT / 128, 2, 4), 256, 0, stream>>>(x, Xt);
    k1_hidden<<<NCHUNK / 4, 256, 0, stream>>>(z, w1, b1, bw1, bb1, bw2, bb2, Hb, biasws);

    for (int c0 = 0; c0 < NCHUNK; c0 += batch) {
        int nc = NCHUNK - c0;
        if (nc > batch) nc = batch;
        dim3 g2(MW / 1024, (nc + 15) / 16, 1);
        k2_wgen<<<g2, 256, 0, stream>>>(w2p, b2p, Hb, Wt, c0, nc);
        k3_conv<<<nc, 256, 0, stream>>>(Xt, Wt, biasws, out, c0);
    }
}

// Round 4
// 302.808 us; speedup vs baseline: 2.6836x; 1.0238x over previous
//
#include <hip/hip_runtime.h>
#include <stdint.h>

// Problem constants
#define TT     48000   // T
#define TK     120     // samples per chunk (T/K)
#define NC     128     // CIN == COUT
#define NA     384     // CIN*KS
#define NZ     64
#define NH     32
#define NK     400
#define NCHUNK 1600    // B*K
#define MW     49152   // CIN*COUT*KS
#define XROWS  48002   // T + 2 zero prefix rows (causal taps)

typedef float f32x4 __attribute__((ext_vector_type(4)));
typedef __bf16 bf16x8 __attribute__((ext_vector_type(8)));

static __device__ __forceinline__ uint16_t f2bf(float f) {
    uint32_t x; __builtin_memcpy(&x, &f, 4);
    return (uint16_t)((x + 0x7fffu + ((x >> 16) & 1u)) >> 16);
}
static __device__ __forceinline__ uint32_t pk2(uint16_t lo, uint16_t hi) {
    return (uint32_t)lo | ((uint32_t)hi << 16);
}

// ---------------------------------------------------------------------------
// k0w: permute+convert w2 -> w2p bf16 [m'][32], m' = c*384 + a  (m = a*128+c)
//      and b2 -> b2p f32 [m'].
// ---------------------------------------------------------------------------
__global__ __launch_bounds__(256) void k0w(
    const float* __restrict__ w2, const float* __restrict__ b2,
    uint16_t* __restrict__ w2p, float* __restrict__ b2p) {
    int m = blockIdx.x * 256 + threadIdx.x;   // 0..49151
    int a = m >> 7, c = m & 127;
    int mp = c * NA + a;
    const float* src = w2 + (size_t)m * NH;
    uint16_t* dst = w2p + (size_t)mp * NH;
#pragma unroll
    for (int i = 0; i < NH; i += 8) {
        float4 v0 = *(const float4*)(src + i);
        float4 v1 = *(const float4*)(src + i + 4);
        uint4 o;
        o.x = pk2(f2bf(v0.x), f2bf(v0.y));
        o.y = pk2(f2bf(v0.z), f2bf(v0.w));
        o.z = pk2(f2bf(v1.x), f2bf(v1.y));
        o.w = pk2(f2bf(v1.z), f2bf(v1.w));
        *(uint4*)(dst + i) = o;
    }
    b2p[mp] = b2[m];
}

// ---------------------------------------------------------------------------
// k0x: transpose x[b][cin][t] f32 -> Xt[b][t+2][cin] bf16 (2 zero prefix rows)
// tile: 128 t x 64 cin per block
// ---------------------------------------------------------------------------
__global__ __launch_bounds__(256) void k0x(
    const float* __restrict__ x, uint16_t* __restrict__ Xt) {
    int t0 = blockIdx.x * 128, cin0 = blockIdx.y * 64, b = blockIdx.z;
    int tid = threadIdx.x;
    __shared__ __align__(16) uint16_t Lt[128][72];   // pad row to 72 (144B)
    const float* xb = x + ((size_t)b * NC + cin0) * TT + t0;
    int cg = (tid & 7) * 8;    // local cin base (0..56)
    int tq = (tid >> 3) * 4;   // local t base   (0..124)
    uint16_t vb[4][8];         // [t][cin]
#pragma unroll
    for (int i = 0; i < 8; ++i) {
        float4 v = *(const float4*)(xb + (size_t)(cg + i) * TT + tq);
        vb[0][i] = f2bf(v.x); vb[1][i] = f2bf(v.y);
        vb[2][i] = f2bf(v.z); vb[3][i] = f2bf(v.w);
    }
#pragma unroll
    for (int j = 0; j < 4; ++j) {
        uint4 o; __builtin_memcpy(&o, vb[j], 16);
        *(uint4*)&Lt[tq + j][cg] = o;
    }
    __syncthreads();
    uint16_t* XtB = Xt + (size_t)b * XROWS * NC;
#pragma unroll
    for (int r = 0; r < 4; ++r) {
        int s = r * 256 + tid;
        int t = s >> 3, cc = s & 7;
        uint4 o = *(uint4*)&Lt[t][cc * 8];
        *(uint4*)(XtB + (size_t)(t0 + t + 2) * NC + cin0 + cc * 8) = o;
    }
    if (blockIdx.x == 0 && blockIdx.y == 0 && tid < 32)
        *(uint4*)(XtB + tid * 8) = make_uint4(0, 0, 0, 0);  // zero rows -2,-1
}

// ---------------------------------------------------------------------------
// k1: 4 chunks per block (one per wave). All weights staged in LDS with
// conflict-free layouts; coalesced global loads.
// ---------------------------------------------------------------------------
__global__ __launch_bounds__(256) void k1_hidden(
    const float* __restrict__ z,
    const float* __restrict__ w1, const float* __restrict__ b1,
    const float* __restrict__ bw1, const float* __restrict__ bb1,
    const float* __restrict__ bw2, const float* __restrict__ bb2,
    uint16_t* __restrict__ Hb, float* __restrict__ biasws) {
    int tid = threadIdx.x, lane = tid & 63, w = tid >> 6;
    int chunk0 = blockIdx.x * 4;
    int b = chunk0 / NK;            // 400 % 4 == 0: all 4 chunks same b
    int k0 = chunk0 - b * NK;

    __shared__ float w1sT[64][33];   // [i][h] transposed, conflict-free reads
    __shared__ float bw1sT[64][33];
    __shared__ float bw2s[128][33];  // [c][j]
    __shared__ float zs[64][4];
    __shared__ float hbs[4][33];
    __shared__ float b1s[32], bb1s[32], bb2s[128];

    {   // stage w1, bw1 (transposed)
        int row = tid >> 3, c0 = (tid & 7) * 8;
        float4 a0 = *(const float4*)(w1 + row * NZ + c0);
        float4 a1 = *(const float4*)(w1 + row * NZ + c0 + 4);
        float4 c0v = *(const float4*)(bw1 + row * NZ + c0);
        float4 c1v = *(const float4*)(bw1 + row * NZ + c0 + 4);
        const float av[8] = {a0.x,a0.y,a0.z,a0.w,a1.x,a1.y,a1.z,a1.w};
        const float cv[8] = {c0v.x,c0v.y,c0v.z,c0v.w,c1v.x,c1v.y,c1v.z,c1v.w};
#pragma unroll
        for (int j = 0; j < 8; ++j) {
            w1sT[c0 + j][row]  = av[j];
            bw1sT[c0 + j][row] = cv[j];
        }
    }
    {   // stage bw2 [128][32]
        int r = tid >> 1, cb = (tid & 1) * 16;
        float4 v0 = *(const float4*)(bw2 + r * NH + cb);
        float4 v1 = *(const float4*)(bw2 + r * NH + cb + 4);
        float4 v2 = *(const float4*)(bw2 + r * NH + cb + 8);
        float4 v3 = *(const float4*)(bw2 + r * NH + cb + 12);
        const float vv[16] = {v0.x,v0.y,v0.z,v0.w,v1.x,v1.y,v1.z,v1.w,
                              v2.x,v2.y,v2.z,v2.w,v3.x,v3.y,v3.z,v3.w};
#pragma unroll
        for (int j = 0; j < 16; ++j) bw2s[r][cb + j] = vv[j];
    }
    if (tid < 64) {
        float4 zv = *(const float4*)(z + ((size_t)b * NZ + tid) * NK + k0);
        zs[tid][0] = zv.x; zs[tid][1] = zv.y; zs[tid][2] = zv.z; zs[tid][3] = zv.w;
    }
    if (tid < 32) { b1s[tid] = b1[tid]; bb1s[tid] = bb1[tid]; }
    if (tid >= 128 && tid < 256) bb2s[tid - 128] = bb2[tid - 128];
    __syncthreads();

    int chunk = chunk0 + w;
    if (lane < NH) {
        float s = b1s[lane];
#pragma unroll
        for (int i = 0; i < NZ; ++i) s = fmaf(w1sT[i][lane], zs[i][w], s);
        Hb[(size_t)chunk * NH + lane] = f2bf(fmaxf(s, 0.f));
    } else {
        int j = lane - NH;
        float s = bb1s[j];
#pragma unroll
        for (int i = 0; i < NZ; ++i) s = fmaf(bw1sT[i][j], zs[i][w], s);
        hbs[w][j] = fmaxf(s, 0.f);
    }

#pragma unroll
    for (int r = 0; r < 2; ++r) {
        int c = r * 64 + lane;
        float s = bb2s[c];
#pragma unroll
        for (int j = 0; j < NH; ++j) s = fmaf(bw2s[c][j], hbs[w][j], s);
        biasws[(size_t)chunk * NC + c] = s;
    }
}

// ---------------------------------------------------------------------------
// k2: MFMA weight materialization with LDS-staged coalesced stores.
// Wave computes 16 tiles (256 m' x 16 chunks), stashes bf16 results in
// LDS [16 chunk][264], then writes 256B-contiguous runs per chunk row.
// ---------------------------------------------------------------------------
__global__ __launch_bounds__(256) void k2_wgen(
    const uint16_t* __restrict__ w2p, const float* __restrict__ b2p,
    const uint16_t* __restrict__ Hb, uint16_t* __restrict__ Wt,
    int chunk0, int nchunk) {
    int tid = threadIdx.x, lane = tid & 63, w = tid >> 6;
    int quad = lane >> 4, li = lane & 15;
    __shared__ __align__(16) uint16_t St[4][16][264];  // pad 256->264: 2-way max

    int clocal = blockIdx.y * 16 + li;
    int cl = clocal < nchunk ? clocal : (nchunk - 1);
    bf16x8 bfrag = *(const bf16x8*)(Hb + (size_t)(chunk0 + cl) * NH + quad * 8);
    int mbase = blockIdx.x * 1024 + w * 256;

#pragma unroll
    for (int t = 0; t < 16; ++t) {
        int mb = mbase + t * 16;
        bf16x8 afrag = *(const bf16x8*)(w2p + (size_t)(mb + li) * NH + quad * 8);
        f32x4 acc = {0.f, 0.f, 0.f, 0.f};
        acc = __builtin_amdgcn_mfma_f32_16x16x32_bf16(afrag, bfrag, acc, 0, 0, 0);
        float4 bias = *(const float4*)(b2p + mb + quad * 4);
        uint16_t p[4] = { f2bf(acc[0] + bias.x), f2bf(acc[1] + bias.y),
                          f2bf(acc[2] + bias.z), f2bf(acc[3] + bias.w) };
        uint64_t pv; __builtin_memcpy(&pv, p, 8);
        *(uint64_t*)&St[w][li][t * 16 + quad * 4] = pv;   // D: row=quad*4+r, col(chunk)=li
    }
    // same-wave LDS readback (compiler inserts lgkmcnt wait; no barrier needed)
#pragma unroll
    for (int p = 0; p < 8; ++p) {
        int ch = (lane >> 4) + (p & 3) * 4;
        int part = lane & 15, mh = p >> 2;
        uint4 v = *(const uint4*)&St[w][ch][mh * 128 + part * 8];
        int cg = blockIdx.y * 16 + ch;
        if (cg < nchunk)
            *(uint4*)(Wt + (size_t)cg * MW + mbase + mh * 128 + part * 8) = v;
    }
}

// ---------------------------------------------------------------------------
// k3: per-chunk conv GEMM via MFMA. Block = chunk, 4 waves, each 64t x 64c.
// v3 changes (theory: W-stage was a 768B-stride 16B gather AND fully
// serialized between two barriers, 6x per block):
//  - W staged per-dk (16 KB granule) into LDS layout [c 128][8 slot][8a],
//    slot XOR'd with (c&7) (pre-swizzled per-lane GLOBAL source; linear LDS
//    dest per rule #21). Source runs are the contiguous 128B per (c,dk) --
//    8x128B segments per instruction instead of 64x16B scatter.
//  - Double-buffered, issue-after-barrier-before-compute (T3 minimum
//    2-phase): the next dk's stage flies under this dk's 32 MFMAs; the next
//    __syncthreads()'s implicit vmcnt(0) is the only wait. 7 barriers/block
//    (was 12), zero exposed stage latency except the prologue.
//  - LDS 32 KB Xa + 2x16 KB W = 64 KB -> 2 blocks/CU.
// Numerics bit-identical to v2 (same data, same MFMA order).
// ---------------------------------------------------------------------------
__global__ __launch_bounds__(256) void k3_conv(
    const uint16_t* __restrict__ Xt, const uint16_t* __restrict__ Wt,
    const float* __restrict__ biasws, float* __restrict__ out, int chunk0) {
    int cl = blockIdx.x, chunk = chunk0 + cl;
    int b = chunk / NK, k = chunk - b * NK;
    int kbase = k * TK;
    int tid = threadIdx.x, lane = tid & 63, w = tid >> 6;
    int quad = lane >> 4, li = lane & 15;
    int tblk = (w & 1) * 64, cblk = (w >> 1) * 64;

    __shared__ __align__(16) char smem[65536];
    char* Xa  = smem;             // 128 rows x 256B (cin-unit XOR-swizzled)
    char* Db0 = smem + 32768;     // W dbuf A: [c 128][8 slot^(c&7)][8a] = 16 KB
    char* Db1 = smem + 49152;     // W dbuf B
    const uint16_t* XtB = Xt + (size_t)b * XROWS * NC;
    const uint16_t* WtC = Wt + (size_t)cl * MW;

    f32x4 acc[4][4];
#pragma unroll
    for (int i = 0; i < 4; ++i)
#pragma unroll
        for (int j = 0; j < 4; ++j) acc[i][j] = (f32x4){0.f, 0.f, 0.f, 0.f};

    // stage of W for one dk: 16 insts/block (4/wave), each 8x128B source runs
    auto stageD = [&](char* dst, int dks) {
#pragma unroll
        for (int j = 0; j < 4; ++j) {
            int g = (w * 4 + j) * 64 + lane;          // 16B-unit index 0..1023
            int c = g >> 3, sd = g & 7;               // 8 units per c
            int o = sd ^ (c & 7);                     // inverse slot swizzle
            const uint16_t* gsrc = WtC + (size_t)c * NA + dks * 64 + o * 8;
            __builtin_amdgcn_global_load_lds(
                (__attribute__((address_space(1))) void*)gsrc,
                (__attribute__((address_space(3))) void*)(dst + (w * 4 + j) * 1024),
                16, 0, 0);
        }
    };

    // prologue: stage raw Xt rows (once) + W(dk=0)
#pragma unroll
    for (int i = 0; i < 8; ++i) {
        int brow = w * 32 + i * 4 + quad;
        const uint16_t* g = XtB + (size_t)(kbase + brow) * NC
                          + ((li ^ (brow & 15)) * 8);
        __builtin_amdgcn_global_load_lds(
            (__attribute__((address_space(1))) void*)g,
            (__attribute__((address_space(3))) void*)(Xa + (w * 32 + i * 4) * 256),
            16, 0, 0);
    }
    stageD(Db0, 0);

#pragma unroll
    for (int dk = 0; dk < 6; ++dk) {
        // implicit vmcnt(0)+lgkmcnt(0) drain: waits for D(dk) (+Xa at dk=0);
        // orders all waves' reads of D(dk-1) before the overwrite below.
        __syncthreads();
        if (dk < 5) stageD((dk & 1) ? Db0 : Db1, dk + 1);   // flies under MFMAs
        char* cur = (dk & 1) ? Db1 : Db0;
        int tap = dk >> 1;

        bf16x8 bfr[2][4];
#pragma unroll
        for (int s = 0; s < 2; ++s)
#pragma unroll
            for (int ct = 0; ct < 4; ++ct) {
                int c = cblk + ct * 16 + li;
                bfr[s][ct] = *(const bf16x8*)(cur + c * 128
                             + (((s * 4 + quad) ^ (c & 7)) << 4));
            }
#pragma unroll
        for (int s = 0; s < 2; ++s) {
            bf16x8 af[4];
#pragma unroll
            for (int tt = 0; tt < 4; ++tt) {
                int r = tblk + tt * 16 + li + 2 - tap;
                r = r > 127 ? 127 : r;     // clamped rows feed only discarded t
                int q = (dk & 1) * 8 + s * 4 + quad;
                af[tt] = *(const bf16x8*)(Xa + r * 256 + ((q ^ (r & 15)) << 4));
            }
#pragma unroll
            for (int tt = 0; tt < 4; ++tt)
#pragma unroll
                for (int ct = 0; ct < 4; ++ct)
                    acc[tt][ct] = __builtin_amdgcn_mfma_f32_16x16x32_bf16(
                        af[tt], bfr[s][ct], acc[tt][ct], 0, 0, 0);
        }
    }

    // epilogue: D col = c = lane&15 (+tile), row = t = quad*4+reg (+tile)
#pragma unroll
    for (int ct = 0; ct < 4; ++ct) {
        int c = cblk + ct * 16 + li;
        float bias = biasws[(size_t)chunk * NC + c];
        float* ob = out + ((size_t)b * NC + c) * TT + kbase;
#pragma unroll
        for (int tt = 0; tt < 4; ++tt) {
            int t0v = tblk + tt * 16 + quad * 4;
            if (t0v < TK) {
                f32x4 v = acc[tt][ct];
                *(float4*)(ob + t0v) = make_float4(v[0] + bias, v[1] + bias,
                                                   v[2] + bias, v[3] + bias);
            }
        }
    }
}

// ---------------------------------------------------------------------------
// launch
// ---------------------------------------------------------------------------
extern "C" void kernel_launch(void* const* d_in, const int* in_sizes, int n_in,
                              void* d_out, int out_size, void* d_ws, size_t ws_size,
                              hipStream_t stream) {
    const float* x   = (const float*)d_in[0];
    const float* z   = (const float*)d_in[1];
    const float* w1  = (const float*)d_in[2];
    const float* b1  = (const float*)d_in[3];
    const float* w2  = (const float*)d_in[4];
    const float* b2  = (const float*)d_in[5];
    const float* bw1 = (const float*)d_in[6];
    const float* bb1 = (const float*)d_in[7];
    const float* bw2 = (const float*)d_in[8];
    const float* bb2 = (const float*)d_in[9];
    float* out = (float*)d_out;

    // ws layout (all 256-aligned):
    char* ws = (char*)d_ws;
    uint16_t* Hb     = (uint16_t*)(ws);                 //   102,400 B
    float*    biasws = (float*)(ws + 102400);           //   819,200 B
    uint16_t* w2p    = (uint16_t*)(ws + 921600);        // 3,145,728 B
    float*    b2p    = (float*)(ws + 4067328);          //   196,608 B
    uint16_t* Xt     = (uint16_t*)(ws + 4263936);       // 49,158,144 B (incl. tail pad)
    const size_t wt_off = 53422080;
    uint16_t* Wt     = (uint16_t*)(ws + wt_off);        // slice buffer

    // L3 blocking: keep the Wt slice resident in Infinity Cache between
    // k2 (producer) and k3 (consumer). 800 chunks -> 78.6 MB slice.
    size_t avail = (ws_size > wt_off) ? (ws_size - wt_off) : 0;
    int batch = (int)(avail / ((size_t)MW * 2));
    if (batch > 800) batch = 800;
    if (batch < 1) batch = 1;

    k0w<<<MW / 256, 256, 0, stream>>>(w2, b2, w2p, b2p);
    k0x<<<dim3(TT / 128, 2, 4), 256, 0, stream>>>(x, Xt);
    k1_hidden<<<NCHUNK / 4, 256, 0, stream>>>(z, w1, b1, bw1, bb1, bw2, bb2, Hb, biasws);

    for (int c0 = 0; c0 < NCHUNK; c0 += batch) {
        int nc = NCHUNK - c0;
        if (nc > batch) nc = batch;
        dim3 g2(MW / 1024, (nc + 15) / 16, 1);
        k2_wgen<<<g2, 256, 0, stream>>>(w2p, b2p, Hb, Wt, c0, nc);
        k3_conv<<<nc, 256, 0, stream>>>(Xt, Wt, biasws, out, c0);
    }
}

// Round 5
// 292.341 us; speedup vs baseline: 2.7797x; 1.0358x over previous
//
#include <hip/hip_runtime.h>
#include <stdint.h>

// Problem constants
#define TT     48000   // T
#define TK     120     // samples per chunk (T/K)
#define NC     128     // CIN == COUT
#define NA     384     // CIN*KS
#define NZ     64
#define NH     32
#define NK     400
#define NCHUNK 1600    // B*K
#define MW     49152   // CIN*COUT*KS
#define XROWS  48002   // T + 2 zero prefix rows (causal taps)

typedef float f32x4 __attribute__((ext_vector_type(4)));
typedef __bf16 bf16x8 __attribute__((ext_vector_type(8)));

static __device__ __forceinline__ uint16_t f2bf(float f) {
    uint32_t x; __builtin_memcpy(&x, &f, 4);
    return (uint16_t)((x + 0x7fffu + ((x >> 16) & 1u)) >> 16);
}
static __device__ __forceinline__ uint32_t pk2(uint16_t lo, uint16_t hi) {
    return (uint32_t)lo | ((uint32_t)hi << 16);
}

// ---------------------------------------------------------------------------
// k0w: permute+convert w2 -> w2p bf16 [m'][32], m' = c*384 + a  (m = a*128+c)
//      and b2 -> b2p f32 [m'].
// ---------------------------------------------------------------------------
__global__ __launch_bounds__(256) void k0w(
    const float* __restrict__ w2, const float* __restrict__ b2,
    uint16_t* __restrict__ w2p, float* __restrict__ b2p) {
    int m = blockIdx.x * 256 + threadIdx.x;   // 0..49151
    int a = m >> 7, c = m & 127;
    int mp = c * NA + a;
    const float* src = w2 + (size_t)m * NH;
    uint16_t* dst = w2p + (size_t)mp * NH;
#pragma unroll
    for (int i = 0; i < NH; i += 8) {
        float4 v0 = *(const float4*)(src + i);
        float4 v1 = *(const float4*)(src + i + 4);
        uint4 o;
        o.x = pk2(f2bf(v0.x), f2bf(v0.y));
        o.y = pk2(f2bf(v0.z), f2bf(v0.w));
        o.z = pk2(f2bf(v1.x), f2bf(v1.y));
        o.w = pk2(f2bf(v1.z), f2bf(v1.w));
        *(uint4*)(dst + i) = o;
    }
    b2p[mp] = b2[m];
}

// ---------------------------------------------------------------------------
// k0x: transpose x[b][cin][t] f32 -> Xt[b][t+2][cin] bf16 (2 zero prefix rows)
// tile: 128 t x 64 cin per block
// ---------------------------------------------------------------------------
__global__ __launch_bounds__(256) void k0x(
    const float* __restrict__ x, uint16_t* __restrict__ Xt) {
    int t0 = blockIdx.x * 128, cin0 = blockIdx.y * 64, b = blockIdx.z;
    int tid = threadIdx.x;
    __shared__ __align__(16) uint16_t Lt[128][72];   // pad row to 72 (144B)
    const float* xb = x + ((size_t)b * NC + cin0) * TT + t0;
    int cg = (tid & 7) * 8;    // local cin base (0..56)
    int tq = (tid >> 3) * 4;   // local t base   (0..124)
    uint16_t vb[4][8];         // [t][cin]
#pragma unroll
    for (int i = 0; i < 8; ++i) {
        float4 v = *(const float4*)(xb + (size_t)(cg + i) * TT + tq);
        vb[0][i] = f2bf(v.x); vb[1][i] = f2bf(v.y);
        vb[2][i] = f2bf(v.z); vb[3][i] = f2bf(v.w);
    }
#pragma unroll
    for (int j = 0; j < 4; ++j) {
        uint4 o; __builtin_memcpy(&o, vb[j], 16);
        *(uint4*)&Lt[tq + j][cg] = o;
    }
    __syncthreads();
    uint16_t* XtB = Xt + (size_t)b * XROWS * NC;
#pragma unroll
    for (int r = 0; r < 4; ++r) {
        int s = r * 256 + tid;
        int t = s >> 3, cc = s & 7;
        uint4 o = *(uint4*)&Lt[t][cc * 8];
        *(uint4*)(XtB + (size_t)(t0 + t + 2) * NC + cin0 + cc * 8) = o;
    }
    if (blockIdx.x == 0 && blockIdx.y == 0 && tid < 32)
        *(uint4*)(XtB + tid * 8) = make_uint4(0, 0, 0, 0);  // zero rows -2,-1
}

// ---------------------------------------------------------------------------
// k1: 4 chunks per block (one per wave). All weights staged in LDS with
// conflict-free layouts; coalesced global loads.
// ---------------------------------------------------------------------------
__global__ __launch_bounds__(256) void k1_hidden(
    const float* __restrict__ z,
    const float* __restrict__ w1, const float* __restrict__ b1,
    const float* __restrict__ bw1, const float* __restrict__ bb1,
    const float* __restrict__ bw2, const float* __restrict__ bb2,
    uint16_t* __restrict__ Hb, float* __restrict__ biasws) {
    int tid = threadIdx.x, lane = tid & 63, w = tid >> 6;
    int chunk0 = blockIdx.x * 4;
    int b = chunk0 / NK;            // 400 % 4 == 0: all 4 chunks same b
    int k0 = chunk0 - b * NK;

    __shared__ float w1sT[64][33];   // [i][h] transposed, conflict-free reads
    __shared__ float bw1sT[64][33];
    __shared__ float bw2s[128][33];  // [c][j]
    __shared__ float zs[64][4];
    __shared__ float hbs[4][33];
    __shared__ float b1s[32], bb1s[32], bb2s[128];

    {   // stage w1, bw1 (transposed)
        int row = tid >> 3, c0 = (tid & 7) * 8;
        float4 a0 = *(const float4*)(w1 + row * NZ + c0);
        float4 a1 = *(const float4*)(w1 + row * NZ + c0 + 4);
        float4 c0v = *(const float4*)(bw1 + row * NZ + c0);
        float4 c1v = *(const float4*)(bw1 + row * NZ + c0 + 4);
        const float av[8] = {a0.x,a0.y,a0.z,a0.w,a1.x,a1.y,a1.z,a1.w};
        const float cv[8] = {c0v.x,c0v.y,c0v.z,c0v.w,c1v.x,c1v.y,c1v.z,c1v.w};
#pragma unroll
        for (int j = 0; j < 8; ++j) {
            w1sT[c0 + j][row]  = av[j];
            bw1sT[c0 + j][row] = cv[j];
        }
    }
    {   // stage bw2 [128][32]
        int r = tid >> 1, cb = (tid & 1) * 16;
        float4 v0 = *(const float4*)(bw2 + r * NH + cb);
        float4 v1 = *(const float4*)(bw2 + r * NH + cb + 4);
        float4 v2 = *(const float4*)(bw2 + r * NH + cb + 8);
        float4 v3 = *(const float4*)(bw2 + r * NH + cb + 12);
        const float vv[16] = {v0.x,v0.y,v0.z,v0.w,v1.x,v1.y,v1.z,v1.w,
                              v2.x,v2.y,v2.z,v2.w,v3.x,v3.y,v3.z,v3.w};
#pragma unroll
        for (int j = 0; j < 16; ++j) bw2s[r][cb + j] = vv[j];
    }
    if (tid < 64) {
        float4 zv = *(const float4*)(z + ((size_t)b * NZ + tid) * NK + k0);
        zs[tid][0] = zv.x; zs[tid][1] = zv.y; zs[tid][2] = zv.z; zs[tid][3] = zv.w;
    }
    if (tid < 32) { b1s[tid] = b1[tid]; bb1s[tid] = bb1[tid]; }
    if (tid >= 128 && tid < 256) bb2s[tid - 128] = bb2[tid - 128];
    __syncthreads();

    int chunk = chunk0 + w;
    if (lane < NH) {
        float s = b1s[lane];
#pragma unroll
        for (int i = 0; i < NZ; ++i) s = fmaf(w1sT[i][lane], zs[i][w], s);
        Hb[(size_t)chunk * NH + lane] = f2bf(fmaxf(s, 0.f));
    } else {
        int j = lane - NH;
        float s = bb1s[j];
#pragma unroll
        for (int i = 0; i < NZ; ++i) s = fmaf(bw1sT[i][j], zs[i][w], s);
        hbs[w][j] = fmaxf(s, 0.f);
    }

#pragma unroll
    for (int r = 0; r < 2; ++r) {
        int c = r * 64 + lane;
        float s = bb2s[c];
#pragma unroll
        for (int j = 0; j < NH; ++j) s = fmaf(bw2s[c][j], hbs[w][j], s);
        biasws[(size_t)chunk * NC + c] = s;
    }
}

// ---------------------------------------------------------------------------
// k2: MFMA weight materialization, v2.
// Theory (round-4 post-mortem): old grid (48,50) re-read ALL of w2p per
// 16-chunk group -> 157 MB/launch of L2/L3 reads, thrashed by the 78 MB
// store stream flowing through the same per-XCD L2s. Fix: block = 256 m'
// slice x 10 chunk-group loop; the wave's 4 afrag tiles (16 VGPR) + 4 bias
// float4 (16 VGPR) load ONCE and stay in registers across the loop.
// w2p reads/launch: 157 MB -> 15 MB; b2p 25 MB -> 1 MB. Stores unchanged
// (78.6 MB = the irreducible Wt). Numerics bit-identical.
// St: 8.7 KB, 2-way max bank aliasing, same-wave readback (no barriers).
// ---------------------------------------------------------------------------
__global__ __launch_bounds__(256) void k2_wgen(
    const uint16_t* __restrict__ w2p, const float* __restrict__ b2p,
    const uint16_t* __restrict__ Hb, uint16_t* __restrict__ Wt,
    int chunk0, int nchunk) {
    int tid = threadIdx.x, lane = tid & 63, w = tid >> 6;
    int quad = lane >> 4, li = lane & 15;
    __shared__ __align__(16) uint16_t St[4][16][68];   // pad 64->68
    int mb = blockIdx.x * 256 + w * 64;                // wave's m' base

    bf16x8 afrag[4];   // loop-invariant A tiles (registers)
    float4 bias[4];
#pragma unroll
    for (int t = 0; t < 4; ++t) {
        afrag[t] = *(const bf16x8*)(w2p + (size_t)(mb + t * 16 + li) * NH + quad * 8);
        bias[t]  = *(const float4*)(b2p + mb + t * 16 + quad * 4);
    }

    for (int g = 0; g < 10; ++g) {
        int cl0 = blockIdx.y * 160 + g * 16;           // local chunk base
        if (cl0 >= nchunk) break;
        int cl = cl0 + li;
        if (cl >= nchunk) cl = nchunk - 1;
        bf16x8 hfrag = *(const bf16x8*)(Hb + (size_t)(chunk0 + cl) * NH + quad * 8);
#pragma unroll
        for (int t = 0; t < 4; ++t) {
            f32x4 acc = {0.f, 0.f, 0.f, 0.f};
            acc = __builtin_amdgcn_mfma_f32_16x16x32_bf16(afrag[t], hfrag, acc, 0, 0, 0);
            uint16_t p[4] = { f2bf(acc[0] + bias[t].x), f2bf(acc[1] + bias[t].y),
                              f2bf(acc[2] + bias[t].z), f2bf(acc[3] + bias[t].w) };
            uint64_t pv; __builtin_memcpy(&pv, p, 8);
            // D: row = quad*4+r (m' offset t*16+quad*4+r), col(chunk) = li
            *(uint64_t*)&St[w][li][t * 16 + quad * 4] = pv;
        }
        // same-wave readback (compiler inserts lgkmcnt wait) + coalesced store
#pragma unroll
        for (int p = 0; p < 2; ++p) {
            int ch = (lane >> 3) + p * 8, part = lane & 7;
            uint4 v = *(const uint4*)&St[w][ch][part * 8];
            int cg = cl0 + ch;
            if (cg < nchunk)
                *(uint4*)(Wt + (size_t)cg * MW + mb + part * 8) = v;
        }
    }
}

// ---------------------------------------------------------------------------
// k3: per-chunk conv GEMM via MFMA (round-4 version, verified).
// Xa staged once (32 KB, XOR-swizzled via pre-swizzled global source);
// W double-buffered 2x16 KB, stage flies under the 32 MFMAs of each dk.
// ---------------------------------------------------------------------------
__global__ __launch_bounds__(256) void k3_conv(
    const uint16_t* __restrict__ Xt, const uint16_t* __restrict__ Wt,
    const float* __restrict__ biasws, float* __restrict__ out, int chunk0) {
    int cl = blockIdx.x, chunk = chunk0 + cl;
    int b = chunk / NK, k = chunk - b * NK;
    int kbase = k * TK;
    int tid = threadIdx.x, lane = tid & 63, w = tid >> 6;
    int quad = lane >> 4, li = lane & 15;
    int tblk = (w & 1) * 64, cblk = (w >> 1) * 64;

    __shared__ __align__(16) char smem[65536];
    char* Xa  = smem;             // 128 rows x 256B (cin-unit XOR-swizzled)
    char* Db0 = smem + 32768;     // W dbuf A: [c 128][8 slot^(c&7)][8a] = 16 KB
    char* Db1 = smem + 49152;     // W dbuf B
    const uint16_t* XtB = Xt + (size_t)b * XROWS * NC;
    const uint16_t* WtC = Wt + (size_t)cl * MW;

    f32x4 acc[4][4];
#pragma unroll
    for (int i = 0; i < 4; ++i)
#pragma unroll
        for (int j = 0; j < 4; ++j) acc[i][j] = (f32x4){0.f, 0.f, 0.f, 0.f};

    // stage of W for one dk: 16 insts/block (4/wave), each 8x128B source runs
    auto stageD = [&](char* dst, int dks) {
#pragma unroll
        for (int j = 0; j < 4; ++j) {
            int g = (w * 4 + j) * 64 + lane;          // 16B-unit index 0..1023
            int c = g >> 3, sd = g & 7;               // 8 units per c
            int o = sd ^ (c & 7);                     // inverse slot swizzle
            const uint16_t* gsrc = WtC + (size_t)c * NA + dks * 64 + o * 8;
            __builtin_amdgcn_global_load_lds(
                (__attribute__((address_space(1))) void*)gsrc,
                (__attribute__((address_space(3))) void*)(dst + (w * 4 + j) * 1024),
                16, 0, 0);
        }
    };

    // prologue: stage raw Xt rows (once) + W(dk=0)
#pragma unroll
    for (int i = 0; i < 8; ++i) {
        int brow = w * 32 + i * 4 + quad;
        const uint16_t* g = XtB + (size_t)(kbase + brow) * NC
                          + ((li ^ (brow & 15)) * 8);
        __builtin_amdgcn_global_load_lds(
            (__attribute__((address_space(1))) void*)g,
            (__attribute__((address_space(3))) void*)(Xa + (w * 32 + i * 4) * 256),
            16, 0, 0);
    }
    stageD(Db0, 0);

#pragma unroll
    for (int dk = 0; dk < 6; ++dk) {
        // implicit vmcnt(0)+lgkmcnt(0) drain: waits for D(dk) (+Xa at dk=0);
        // orders all waves' reads of D(dk-1) before the overwrite below.
        __syncthreads();
        if (dk < 5) stageD((dk & 1) ? Db0 : Db1, dk + 1);   // flies under MFMAs
        char* cur = (dk & 1) ? Db1 : Db0;
        int tap = dk >> 1;

        bf16x8 bfr[2][4];
#pragma unroll
        for (int s = 0; s < 2; ++s)
#pragma unroll
            for (int ct = 0; ct < 4; ++ct) {
                int c = cblk + ct * 16 + li;
                bfr[s][ct] = *(const bf16x8*)(cur + c * 128
                             + (((s * 4 + quad) ^ (c & 7)) << 4));
            }
#pragma unroll
        for (int s = 0; s < 2; ++s) {
            bf16x8 af[4];
#pragma unroll
            for (int tt = 0; tt < 4; ++tt) {
                int r = tblk + tt * 16 + li + 2 - tap;
                r = r > 127 ? 127 : r;     // clamped rows feed only discarded t
                int q = (dk & 1) * 8 + s * 4 + quad;
                af[tt] = *(const bf16x8*)(Xa + r * 256 + ((q ^ (r & 15)) << 4));
            }
#pragma unroll
            for (int tt = 0; tt < 4; ++tt)
#pragma unroll
                for (int ct = 0; ct < 4; ++ct)
                    acc[tt][ct] = __builtin_amdgcn_mfma_f32_16x16x32_bf16(
                        af[tt], bfr[s][ct], acc[tt][ct], 0, 0, 0);
        }
    }

    // epilogue: D col = c = lane&15 (+tile), row = t = quad*4+reg (+tile)
#pragma unroll
    for (int ct = 0; ct < 4; ++ct) {
        int c = cblk + ct * 16 + li;
        float bias = biasws[(size_t)chunk * NC + c];
        float* ob = out + ((size_t)b * NC + c) * TT + kbase;
#pragma unroll
        for (int tt = 0; tt < 4; ++tt) {
            int t0v = tblk + tt * 16 + quad * 4;
            if (t0v < TK) {
                f32x4 v = acc[tt][ct];
                *(float4*)(ob + t0v) = make_float4(v[0] + bias, v[1] + bias,
                                                   v[2] + bias, v[3] + bias);
            }
        }
    }
}

// ---------------------------------------------------------------------------
// launch
// ---------------------------------------------------------------------------
extern "C" void kernel_launch(void* const* d_in, const int* in_sizes, int n_in,
                              void* d_out, int out_size, void* d_ws, size_t ws_size,
                              hipStream_t stream) {
    const float* x   = (const float*)d_in[0];
    const float* z   = (const float*)d_in[1];
    const float* w1  = (const float*)d_in[2];
    const float* b1  = (const float*)d_in[3];
    const float* w2  = (const float*)d_in[4];
    const float* b2  = (const float*)d_in[5];
    const float* bw1 = (const float*)d_in[6];
    const float* bb1 = (const float*)d_in[7];
    const float* bw2 = (const float*)d_in[8];
    const float* bb2 = (const float*)d_in[9];
    float* out = (float*)d_out;

    // ws layout (all 256-aligned):
    char* ws = (char*)d_ws;
    uint16_t* Hb     = (uint16_t*)(ws);                 //   102,400 B
    float*    biasws = (float*)(ws + 102400);           //   819,200 B
    uint16_t* w2p    = (uint16_t*)(ws + 921600);        // 3,145,728 B
    float*    b2p    = (float*)(ws + 4067328);          //   196,608 B
    uint16_t* Xt     = (uint16_t*)(ws + 4263936);       // 49,158,144 B (incl. tail pad)
    const size_t wt_off = 53422080;
    uint16_t* Wt     = (uint16_t*)(ws + wt_off);        // slice buffer

    // L3 blocking: keep the Wt slice resident in Infinity Cache between
    // k2 (producer) and k3 (consumer). 800 chunks -> 78.6 MB slice
    // (78 Wt + 25 Xt + 49 out = 152 MB < 256 MB L3).
    size_t avail = (ws_size > wt_off) ? (ws_size - wt_off) : 0;
    int batch = (int)(avail / ((size_t)MW * 2));
    if (batch > 800) batch = 800;
    if (batch < 1) batch = 1;

    k0w<<<MW / 256, 256, 0, stream>>>(w2, b2, w2p, b2p);
    k0x<<<dim3(TT / 128, 2, 4), 256, 0, stream>>>(x, Xt);
    k1_hidden<<<NCHUNK / 4, 256, 0, stream>>>(z, w1, b1, bw1, bb1, bw2, bb2, Hb, biasws);

    for (int c0 = 0; c0 < NCHUNK; c0 += batch) {
        int nc = NCHUNK - c0;
        if (nc > batch) nc = batch;
        dim3 g2(MW / 256, (nc + 159) / 160, 1);
        k2_wgen<<<g2, 256, 0, stream>>>(w2p, b2p, Hb, Wt, c0, nc);
        k3_conv<<<nc, 256, 0, stream>>>(Xt, Wt, biasws, out, c0);
    }
}